// Round 6
// baseline (232.310 us; speedup 1.0000x reference)
//
#include <hip/hip_runtime.h>

// GroupSort: x[32,256,64,64] fp32. For each channel pair (2k, 2k+1):
//   d = x[2k] - x[2k+1]; r = relu(d); out[2k] = x[2k] - r  (= min)
//   out[2k+1] = x[2k+1] + r  (= max)
// Pure streaming op: 128 MiB in + 128 MiB out, zero reuse within one call.
//
// Ladder (kernel-dispatch time; dur_us = kernel + ~160 us harness fills):
//  R0: nt+nt, 32B-interleaved pairs           -> ~69 us
//  R1: nt+nt, contiguous 1 KiB wave txns      -> ~62 us
//  R2: plain+nt, strided, flat grid           -> ~80 us  REGRESSION
//  R3: nt+nt, persistent grid + dbl pipeline  -> ~62-66 us
//  R4: plain+nt on R3 structure               -> ~83 us  REGRESSION (x2 confirm)
//  R5: nt+plain on R3 structure               -> ~64 us  flat
//  R6 (this): plain+plain — the LAST cell of the ld/st policy matrix,
//      and the exact config of both high-BW references (fill 6.7 TB/s,
//      m13 copy 6.29 TB/s). Theory: plain-load penalty in R2/R4 was an
//      INTERACTION with nt stores (L2 allocate path fighting raw MC store
//      stream). plain+plain lets L2 mediate both streams and batch
//      full-line writebacks. If flat/regressed: matrix complete, nt+nt
//      is the floor -> restore R3, declare roofline.
//
// Layout: plane = 1024 float4. u in [0, 2^21): pair = u>>9,
// within = u&511; thread covers base+{0,512} (even) and +{1024,1536} (odd).

typedef float f32x4 __attribute__((ext_vector_type(4)));

__device__ __forceinline__ void pair_op(const f32x4 a, const f32x4 b,
                                        f32x4& lo, f32x4& hi) {
#pragma unroll
    for (int i = 0; i < 4; ++i) {
        float d = a[i] - b[i];
        float r = d > 0.0f ? d : 0.0f;
        lo[i] = a[i] - r;
        hi[i] = b[i] + r;
    }
}

__device__ __forceinline__ long base_of(long u) {
    const long pair   = u >> 9;
    const long within = u & 511;
    return pair * 2048 + within;
}

#define NTHREADS_TOTAL (2048L * 256L)   // 524288; 32 waves/CU resident
#define NITER 4                         // 524288 * 4 = 2^21 work units

__global__ __launch_bounds__(256, 8) void groupsort_kernel(
    const f32x4* __restrict__ x, f32x4* __restrict__ out) {
    const long t = (long)blockIdx.x * blockDim.x + threadIdx.x;

    long u = t;
    long base = base_of(u);
    f32x4 a0 = x[base];
    f32x4 a1 = x[base + 512];
    f32x4 b0 = x[base + 1024];
    f32x4 b1 = x[base + 1536];

#pragma unroll
    for (int it = 0; it < NITER; ++it) {
        long nbase = 0;
        f32x4 na0, na1, nb0, nb1;
        if (it < NITER - 1) {               // compile-time after unroll
            nbase = base_of(u + NTHREADS_TOTAL);
            na0 = x[nbase];
            na1 = x[nbase + 512];
            nb0 = x[nbase + 1024];
            nb1 = x[nbase + 1536];
        }

        f32x4 lo0, hi0, lo1, hi1;
        pair_op(a0, b0, lo0, hi0);
        pair_op(a1, b1, lo1, hi1);
        out[base]        = lo0;   // plain stores: L2 write-combine path
        out[base + 512]  = lo1;
        out[base + 1024] = hi0;
        out[base + 1536] = hi1;

        if (it < NITER - 1) {
            base = nbase;
            a0 = na0; a1 = na1; b0 = nb0; b1 = nb1;
            u += NTHREADS_TOTAL;
        }
    }
}

extern "C" void kernel_launch(void* const* d_in, const int* in_sizes, int n_in,
                              void* d_out, int out_size, void* d_ws, size_t ws_size,
                              hipStream_t stream) {
    const f32x4* x = (const f32x4*)d_in[0];
    f32x4* out = (f32x4*)d_out;
    const int threads = 256;
    const int blocks = 2048;   // 8 blocks/CU x 4 waves = 32 waves/CU resident
    groupsort_kernel<<<blocks, threads, 0, stream>>>(x, out);
}

// Round 7
// 223.058 us; speedup vs baseline: 1.0415x; 1.0415x over previous
//
#include <hip/hip_runtime.h>

// GroupSort: x[32,256,64,64] fp32. For each channel pair (2k, 2k+1):
//   d = x[2k] - x[2k+1]; r = relu(d); out[2k] = x[2k] - r  (= min)
//   out[2k+1] = x[2k+1] + r  (= max)
// Pure streaming op: 128 MiB in + 128 MiB out, zero reuse within one call.
//
// FINAL CONFIG (restored R3 — best of 7 measured variants, 221.8 us):
//   nt loads + nt stores, contiguous 1 KiB wave transactions,
//   persistent grid (2048 blocks = 32 waves/CU), depth-1 pipeline.
//
// Complete measured ladder (kernel dispatch; dur_us = kernel + ~160 us
// harness poison-fills, which are fixed cost):
//  R0: nt+nt, 32B-interleaved pairs           -> ~69 us
//  R1: nt+nt, contiguous 1 KiB wave txns      -> ~62 us
//  R2: plain+nt, strided, flat grid           -> ~80 us  REGRESSION
//  R3: nt+nt, persistent grid + pipeline      -> ~62-66 us  BEST
//  R4: plain+nt on R3 structure               -> ~83 us  REGRESSION
//  R5: nt+plain on R3 structure               -> ~64 us  flat
//  R6: plain+plain on R3 structure            -> ~72 us  REGRESSION
// => ld/st policy matrix complete: plain loads cost 8-20 us unconditionally
//    (L2 allocate path on a touch-once stream); store policy ~neutral.
//    nt+nt is the empirical floor. Remaining gap to the 42.6 us copy
//    roofline (268 MB @ 6.29 TB/s) is mixed-stream DRAM efficiency for
//    this 8 KiB-strided 4-stream read+write shape — no source-level
//    variable moved it (coalescing, occupancy, pipelining, cache policy
//    all measured).
//
// Layout: plane = 1024 float4. u in [0, 2^21): pair = u>>9,
// within = u&511; thread covers base+{0,512} (even) and +{1024,1536} (odd).

typedef float f32x4 __attribute__((ext_vector_type(4)));

__device__ __forceinline__ f32x4 nt_load4(const f32x4* p) {
    return __builtin_nontemporal_load(p);
}
__device__ __forceinline__ void nt_store4(f32x4* p, f32x4 v) {
    __builtin_nontemporal_store(v, p);
}

__device__ __forceinline__ void pair_op(const f32x4 a, const f32x4 b,
                                        f32x4& lo, f32x4& hi) {
#pragma unroll
    for (int i = 0; i < 4; ++i) {
        float d = a[i] - b[i];
        float r = d > 0.0f ? d : 0.0f;
        lo[i] = a[i] - r;
        hi[i] = b[i] + r;
    }
}

__device__ __forceinline__ long base_of(long u) {
    const long pair   = u >> 9;
    const long within = u & 511;
    return pair * 2048 + within;
}

#define NTHREADS_TOTAL (2048L * 256L)   // 524288; 32 waves/CU resident
#define NITER 4                         // 524288 * 4 = 2^21 work units

__global__ __launch_bounds__(256, 8) void groupsort_kernel(
    const f32x4* __restrict__ x, f32x4* __restrict__ out) {
    const long t = (long)blockIdx.x * blockDim.x + threadIdx.x;

    long u = t;
    long base = base_of(u);
    f32x4 a0 = nt_load4(x + base);
    f32x4 a1 = nt_load4(x + base + 512);
    f32x4 b0 = nt_load4(x + base + 1024);
    f32x4 b1 = nt_load4(x + base + 1536);

#pragma unroll
    for (int it = 0; it < NITER; ++it) {
        long nbase = 0;
        f32x4 na0, na1, nb0, nb1;
        if (it < NITER - 1) {               // compile-time after unroll
            nbase = base_of(u + NTHREADS_TOTAL);
            na0 = nt_load4(x + nbase);
            na1 = nt_load4(x + nbase + 512);
            nb0 = nt_load4(x + nbase + 1024);
            nb1 = nt_load4(x + nbase + 1536);
        }

        f32x4 lo0, hi0, lo1, hi1;
        pair_op(a0, b0, lo0, hi0);
        pair_op(a1, b1, lo1, hi1);
        nt_store4(out + base,        lo0);
        nt_store4(out + base + 512,  lo1);
        nt_store4(out + base + 1024, hi0);
        nt_store4(out + base + 1536, hi1);

        if (it < NITER - 1) {
            base = nbase;
            a0 = na0; a1 = na1; b0 = nb0; b1 = nb1;
            u += NTHREADS_TOTAL;
        }
    }
}

extern "C" void kernel_launch(void* const* d_in, const int* in_sizes, int n_in,
                              void* d_out, int out_size, void* d_ws, size_t ws_size,
                              hipStream_t stream) {
    const f32x4* x = (const f32x4*)d_in[0];
    f32x4* out = (f32x4*)d_out;
    const int threads = 256;
    const int blocks = 2048;   // 8 blocks/CU x 4 waves = 32 waves/CU resident
    groupsort_kernel<<<blocks, threads, 0, stream>>>(x, out);
}